// Round 20
// baseline (29.629 us; speedup 1.0000x reference)
//
#include <hip/hip_runtime.h>

// CubeLens: radial lens deflection + bilinear gather + 4x4 avg pool.
// C=64, NS=256, NL=192, UPS=4. Output (64,192,192) fp32.
//
// FINAL (= R14, best measured: 29.40 us; baseline was 91.7).
// Structure: k1 fp32->fp16 channel-last transpose (measured 3.5us incl.
// launch, at its 25MB traffic floor); k2 wave-synchronous gather:
//   1A lane=(2px,tap): geometry + footprint butterflies -> LDS tap table
//   T14: issue 16 batched f16x8 corner loads (coalesced 128B per pixel
//        group) before weights
//   1B lane=(px,corner): corner weights from tap table (batched LDS reads)
//   2:  pure FMA on landed loads; rare wide-span pixels take per-tap path
//   epilogue: LDS repack -> nontemporal f32x4 coalesced stores
// Proven-essential levers: channel-last coalescing (R12: -70% without),
// minimal batched load count (R16: -30% at 4x), fp16 ws (R6: +9%).
// Proven-null: barrier elimination, VGPR caps, occupancy 2x, tables,
// fusion, box staging. Floor is structure-independent at ~29.4us under
// this harness (cold-cache replay + no pipe >11% busy in any profile).

#define NSRC 256
#define NLENS 192
#define NPIX (NLENS * NLENS)     // 36864
#define CSZ  64
#define PXB  32                  // pixels per block (8 per wave)
#define NBLK (NPIX / PXB)        // 1152, divisible by 8
#define NTTILE (NSRC * NSRC / 64)  // 1024 transpose tiles

typedef float    f32x4 __attribute__((ext_vector_type(4)));
typedef _Float16 f16x8 __attribute__((ext_vector_type(8)));

// wave-local LDS sync: drain LDS ops, then stop compiler/scheduler motion
#define WAVE_SYNC() do {                                   \
    asm volatile("s_waitcnt lgkmcnt(0)" ::: "memory");     \
    __builtin_amdgcn_wave_barrier();                       \
    __builtin_amdgcn_sched_barrier(0);                     \
} while (0)

// ---------------- fallback (round-1 kernel, used only if ws too small) ------
__global__ __launch_bounds__(256) void cubelens_fallback(
    const float* __restrict__ src, const float* __restrict__ theta_p,
    float* __restrict__ out)
{
    const float tE = theta_p[0];
    const int pix = blockIdx.x * 256 + threadIdx.x;
    const int c0  = blockIdx.y * 8;
    const int lx  = pix % NLENS;
    const int ly  = pix / NLENS;
    float acc[8];
#pragma unroll
    for (int c = 0; c < 8; ++c) acc[c] = 0.0f;
    const float* __restrict__ srcg = src + (size_t)c0 * (NSRC * NSRC);
#pragma unroll
    for (int uy = 0; uy < 4; ++uy) {
        const float thy = ((float)(ly * 4 + uy) - 383.5f) * 0.01f;
#pragma unroll
        for (int ux = 0; ux < 4; ++ux) {
            const float thx = ((float)(lx * 4 + ux) - 383.5f) * 0.01f;
            const float r  = sqrtf(thx * thx + thy * thy) + 1e-8f;
            const float fx = (thx - (tE * thx) / r) / 0.02f + 127.5f;
            const float fy = (thy - (tE * thy) / r) / 0.02f + 127.5f;
            const bool inb = (fx >= 0.0f) & (fx <= 255.0f) &
                             (fy >= 0.0f) & (fy <= 255.0f);
            if (!inb) continue;
            int x0 = min(max((int)floorf(fx), 0), 254);
            int y0 = min(max((int)floorf(fy), 0), 254);
            const float wx = fminf(fmaxf(fx - (float)x0, 0.0f), 1.0f);
            const float wy = fminf(fmaxf(fy - (float)y0, 0.0f), 1.0f);
            const float w00 = (1.0f - wy) * (1.0f - wx);
            const float w01 = (1.0f - wy) * wx;
            const float w10 = wy * (1.0f - wx);
            const float w11 = wy * wx;
            const float* __restrict__ p = srcg + y0 * NSRC + x0;
#pragma unroll
            for (int c = 0; c < 8; ++c) {
                const float* __restrict__ pc = p + c * (NSRC * NSRC);
                acc[c] += w00 * pc[0] + w01 * pc[1]
                        + w10 * pc[NSRC] + w11 * pc[NSRC + 1];
            }
        }
    }
#pragma unroll
    for (int c = 0; c < 8; ++c)
        out[(size_t)(c0 + c) * NPIX + pix] = acc[c] * 0.0625f;
}

// ---------------- k1: transpose (c,p) fp32 -> (p,c) fp16, XCD swizzle -------
__global__ __launch_bounds__(256) void transpose_kernel(
    const float* __restrict__ src, _Float16* __restrict__ ws)
{
    __shared__ float tile[CSZ][65];
    const int b = blockIdx.x;
    const int tileid = (b & 7) * (NTTILE / 8) + (b >> 3);
    const int p0 = tileid * 64;
    const int t  = threadIdx.x;
    {
        const int crow = t >> 4;
        const int px4  = (t & 15) * 4;
#pragma unroll
        for (int i = 0; i < 4; ++i) {
            const int c = crow + 16 * i;
            const f32x4 v = __builtin_nontemporal_load(
                (const f32x4*)(src + (size_t)c * (NSRC * NSRC) + p0 + px4));
            tile[c][px4 + 0] = v.x; tile[c][px4 + 1] = v.y;
            tile[c][px4 + 2] = v.z; tile[c][px4 + 3] = v.w;
        }
    }
    __syncthreads();
    {
        const int c8 = (t & 7) * 8;
        const int pr = t >> 3;
#pragma unroll
        for (int i = 0; i < 2; ++i) {
            const int p = pr + 32 * i;
            f16x8 h;
#pragma unroll
            for (int k = 0; k < 8; ++k) h[k] = (_Float16)tile[c8 + k][p];
            *(f16x8*)(ws + (size_t)(p0 + p) * CSZ + c8) = h;
        }
    }
}

// ---------------- k2: lens gather, wave-synchronous -------------------------
struct Tap { int x0, y0; float wx, wy; bool inb; };

__device__ __forceinline__ Tap tapgeom(int p, int sub, float tE) {
    const int lx = p % NLENS, ly = p / NLENS;
    const float thy = ((float)(ly * 4 + (sub >> 2)) - 383.5f) * 0.01f;
    const float thx = ((float)(lx * 4 + (sub & 3))  - 383.5f) * 0.01f;
    const float r  = sqrtf(thx * thx + thy * thy) + 1e-8f;
    const float fx = (thx - (tE * thx) / r) / 0.02f + 127.5f;
    const float fy = (thy - (tE * thy) / r) / 0.02f + 127.5f;
    Tap tp;
    tp.inb = (fx >= 0.0f) & (fx <= 255.0f) & (fy >= 0.0f) & (fy <= 255.0f);
    tp.x0 = min(max((int)floorf(fx), 0), 254);
    tp.y0 = min(max((int)floorf(fy), 0), 254);
    tp.wx = fminf(fmaxf(fx - (float)tp.x0, 0.0f), 1.0f);
    tp.wy = fminf(fmaxf(fy - (float)tp.y0, 0.0f), 1.0f);
    return tp;
}

__global__ __launch_bounds__(256, 3) void cubelens_main(
    const _Float16* __restrict__ ws,    // (256,256,64) fp16
    const float* __restrict__ theta_p,
    float* __restrict__ out)            // (64,192,192) fp32
{
    __shared__ f32x4 Btap[PXB][16];
    __shared__ float wpatch[PXB][16];
    __shared__ int   gbase[PXB];
    __shared__ int   gmode[PXB];
    __shared__ float smemO[CSZ][PXB + 1];

    const float tE = theta_p[0];
    const int b = blockIdx.x;
    const int pixblock = (b & 7) * (NBLK / 8) + (b >> 3);   // XCD swizzle
    const int p0 = pixblock * PXB;
    const int t  = threadIdx.x;
    const int lane = t & 63;
    const int wv   = t >> 6;            // wave id: owns pixels 8wv..8wv+7

    // ---- 1A: tap geometry; group g=(t>>4) -> pixels 2g,2g+1 (wave-local) --
    {
        const int g = t >> 4, sub = t & 15;
#pragma unroll
        for (int h = 0; h < 2; ++h) {
            const int pi = 2 * g + h;
            const Tap tp = tapgeom(p0 + pi, sub, tE);
            const float x0f = (float)tp.x0, y0f = (float)tp.y0;
            float mnx = tp.inb ? x0f : 1e9f;
            float mny = tp.inb ? y0f : 1e9f;
#pragma unroll
            for (int off = 1; off < 16; off <<= 1) {
                mnx = fminf(mnx, __shfl_xor(mnx, off, 16));
                mny = fminf(mny, __shfl_xor(mny, off, 16));
            }
            const bool allout = (mnx > 5e8f);
            int viol = (tp.inb & ((x0f > mnx + 2.0f) | (y0f > mny + 2.0f))) ? 1 : 0;
#pragma unroll
            for (int off = 1; off < 16; off <<= 1)
                viol |= __shfl_xor(viol, off, 16);
            const float bxc = fminf(mnx, 252.0f);
            const float byc = fminf(mny, 252.0f);
            f32x4 rec;
            rec.x = tp.inb ? (x0f - bxc) : -1000.0f;
            rec.y = tp.inb ? (y0f - byc) : -1000.0f;
            rec.z = tp.wx;
            rec.w = tp.wy;
            Btap[pi][sub] = rec;
            if (sub == 0) {
                gbase[pi] = (((int)byc) * NSRC + (int)bxc) * CSZ;
                gmode[pi] = allout ? 0 : (viol ? 2 : 1);
            }
        }
    }
    WAVE_SYNC();   // wave's own Btap/gbase/gmode visible to its lanes

    // ---- T14 issue-early: 16 corner loads for this thread's phase-2 px ----
    const int pi2 = t >> 3, c8 = t & 7;
    const int mode2 = gmode[pi2];
    f16x8 v[16];
    if (mode2 == 1) {
        const _Float16* __restrict__ base = ws + gbase[pi2] + c8 * 8;
#pragma unroll
        for (int cn = 0; cn < 16; ++cn)
            v[cn] = *(const f16x8*)(base + ((cn >> 2) * NSRC + (cn & 3)) * CSZ);
    }

    // ---- 1B: corner weights while loads fly; wave-local pixel map ----
    {
        const int sub = t & 15;
        const float cxf = (float)(sub & 3), cyf = (float)(sub >> 2);
#pragma unroll
        for (int h = 0; h < 2; ++h) {
            const int pi = 8 * wv + 2 * (lane >> 4) + h;
            float myw = 0.0f;
#pragma unroll
            for (int j = 0; j < 16; ++j) {
                const f32x4 r = Btap[pi][j];
                const float tx = cxf - r.x;
                const float ty = cyf - r.y;
                const float wxp = (tx == 0.0f) ? (1.0f - r.z)
                                : ((tx == 1.0f) ? r.z : 0.0f);
                const float wyp = (ty == 0.0f) ? (1.0f - r.w)
                                : ((ty == 1.0f) ? r.w : 0.0f);
                myw += wxp * wyp;
            }
            wpatch[pi][sub] = myw * 0.0625f;
        }
    }
    WAVE_SYNC();   // wave's own wpatch visible

    // ---- phase 2: FMA on landed loads ----
    {
        float acc[8];
#pragma unroll
        for (int e = 0; e < 8; ++e) acc[e] = 0.0f;

        if (mode2 == 1) {
#pragma unroll
            for (int cn = 0; cn < 16; ++cn) {
                const float w = wpatch[pi2][cn];
#pragma unroll
                for (int e = 0; e < 8; ++e)
                    acc[e] += w * (float)v[cn][e];     // v_fma_mix_f32
            }
        } else if (mode2 == 2) {
            for (int tap = 0; tap < 16; ++tap) {
                const Tap tp = tapgeom(p0 + pi2, tap, tE);
                if (tp.inb) {
                    const _Float16* __restrict__ pp =
                        ws + (tp.y0 * NSRC + tp.x0) * CSZ + c8 * 8;
                    const f16x8 v00 = *(const f16x8*)(pp);
                    const f16x8 v01 = *(const f16x8*)(pp + CSZ);
                    const f16x8 v10 = *(const f16x8*)(pp + NSRC * CSZ);
                    const f16x8 v11 = *(const f16x8*)(pp + NSRC * CSZ + CSZ);
                    const float w00 = (1.0f - tp.wy) * (1.0f - tp.wx);
                    const float w01 = (1.0f - tp.wy) * tp.wx;
                    const float w10 = tp.wy * (1.0f - tp.wx);
                    const float w11 = tp.wy * tp.wx;
#pragma unroll
                    for (int e = 0; e < 8; ++e)
                        acc[e] += w00 * (float)v00[e] + w01 * (float)v01[e]
                                + w10 * (float)v10[e] + w11 * (float)v11[e];
                }
            }
#pragma unroll
            for (int e = 0; e < 8; ++e) acc[e] *= 0.0625f;
        }

#pragma unroll
        for (int e = 0; e < 8; ++e) smemO[c8 * 8 + e][pi2] = acc[e];
    }
    __syncthreads();   // epilogue reads all 32 px across waves

    // ---- epilogue: coalesced nontemporal f32x4 stores ----
    {
        const int c   = t >> 2;
        const int px8 = (t & 3) * 8;
        float* op = out + (size_t)c * NPIX + p0 + px8;
        f32x4 v0, v1;
        v0.x = smemO[c][px8 + 0]; v0.y = smemO[c][px8 + 1];
        v0.z = smemO[c][px8 + 2]; v0.w = smemO[c][px8 + 3];
        v1.x = smemO[c][px8 + 4]; v1.y = smemO[c][px8 + 5];
        v1.z = smemO[c][px8 + 6]; v1.w = smemO[c][px8 + 7];
        __builtin_nontemporal_store(v0, (f32x4*)op);
        __builtin_nontemporal_store(v1, (f32x4*)(op + 4));
    }
}

extern "C" void kernel_launch(void* const* d_in, const int* in_sizes, int n_in,
                              void* d_out, int out_size, void* d_ws, size_t ws_size,
                              hipStream_t stream) {
    const float* src   = (const float*)d_in[0];
    const float* theta = (const float*)d_in[1];
    float* out = (float*)d_out;

    const size_t need = (size_t)CSZ * NSRC * NSRC * sizeof(_Float16);  // 8.4 MB
    if (ws_size >= need) {
        _Float16* ws = (_Float16*)d_ws;
        transpose_kernel<<<dim3(NTTILE), dim3(256), 0, stream>>>(src, ws);
        cubelens_main<<<dim3(NBLK), dim3(256), 0, stream>>>(ws, theta, out);
    } else {
        cubelens_fallback<<<dim3(NPIX / 256, 8), dim3(256), 0, stream>>>(src, theta, out);
    }
}